// Round 8
// baseline (609.878 us; speedup 1.0000x reference)
//
#include <hip/hip_runtime.h>
#include <hip/hip_bf16.h>
#include <math.h>

#define DIM 64
#define BSHIFT 9
#define BNODES 512   // 1 << BSHIFT
#define MAXB 256     // max coarse buckets (N <= 131072)
#define EPT 8
#define CHUNK 2048   // EPT * 256
#define SPAD 16      // stats padding: 1 counter per 64-B cache line

typedef __attribute__((ext_vector_type(8))) short bf16x8;
typedef __attribute__((ext_vector_type(4))) float f32x4;
typedef __attribute__((ext_vector_type(4))) unsigned int u32x4;

__device__ __forceinline__ short f2bf(float x) {
    union { __hip_bfloat16 b; short s; } u;
    u.b = __float2bfloat16(x);
    return u.s;
}
__device__ __forceinline__ float bf2f(short s) {
    return __uint_as_float(((unsigned)(unsigned short)s) << 16);
}

// ---------------- CSR build: binned 2-pass sort ----------------

__global__ void bin_count_kernel(const int* __restrict__ dst, int* __restrict__ bucket_cnt, int E) {
    __shared__ int h[MAXB];
    int t = threadIdx.x;
    h[t] = 0;
    __syncthreads();
    for (int i = blockIdx.x * blockDim.x + t; i < E; i += gridDim.x * blockDim.x)
        atomicAdd(&h[dst[i] >> BSHIFT], 1);
    __syncthreads();
    if (h[t]) atomicAdd(&bucket_cnt[t], h[t]);
}

__global__ void bucket_scan_kernel(const int* __restrict__ bucket_cnt,
                                   int* __restrict__ bucket_off, int* __restrict__ bucket_fill) {
    __shared__ int s[MAXB];
    int t = threadIdx.x;
    int v = bucket_cnt[t];
    s[t] = v;
    __syncthreads();
    for (int off = 1; off < MAXB; off <<= 1) {
        int x = (t >= off) ? s[t - off] : 0;
        __syncthreads();
        s[t] += x;
        __syncthreads();
    }
    bucket_off[t] = s[t] - v;
    bucket_fill[t] = 0;
}

__global__ __launch_bounds__(256) void bin_scatter_kernel(
    const int* __restrict__ src, const int* __restrict__ dst,
    const int* __restrict__ bucket_off, int* __restrict__ bucket_fill,
    unsigned long long* __restrict__ binned, int E) {
    __shared__ int lcnt[MAXB];
    __shared__ int lbase[MAXB];
    int t = threadIdx.x;
    lcnt[t] = 0;
    __syncthreads();
    int base = blockIdx.x * CHUNK;
    unsigned long long pair[EPT];
    int slot[EPT];
#pragma unroll
    for (int j = 0; j < EPT; j++) {
        int idx = base + j * 256 + t;
        if (idx < E) {
            int s = src[idx], d = dst[idx];
            pair[j] = ((unsigned long long)(unsigned)d << 32) | (unsigned)s;
            slot[j] = atomicAdd(&lcnt[d >> BSHIFT], 1);
        } else {
            slot[j] = -1;
        }
    }
    __syncthreads();
    int c = lcnt[t];
    if (c) lbase[t] = atomicAdd(&bucket_fill[t], c);
    __syncthreads();
#pragma unroll
    for (int j = 0; j < EPT; j++) {
        if (slot[j] >= 0) {
            int b = (int)(pair[j] >> 32) >> BSHIFT;
            binned[(size_t)bucket_off[b] + lbase[b] + slot[j]] = pair[j];
        }
    }
}

// One block per bucket: per-node count -> LDS scan -> row_ptr write -> scatter.
__global__ __launch_bounds__(256) void bucket_csr_kernel(
    const unsigned long long* __restrict__ binned, const int* __restrict__ bucket_off,
    const int* __restrict__ bucket_cnt, int* __restrict__ row_ptr,
    int* __restrict__ src_sorted, int N, int E) {
    __shared__ int cnt[BNODES];
    __shared__ int base[BNODES];
    __shared__ int sdata[256];
    int b = blockIdx.x, t = threadIdx.x;
    cnt[t] = 0; cnt[t + 256] = 0;
    __syncthreads();
    int s0 = bucket_off[b], c = bucket_cnt[b];
    for (int i = t; i < c; i += 256) {
        int d = (int)(binned[(size_t)s0 + i] >> 32);
        atomicAdd(&cnt[d & (BNODES - 1)], 1);
    }
    __syncthreads();
    int v0 = cnt[2 * t], v1 = cnt[2 * t + 1];
    int tsum = v0 + v1;
    sdata[t] = tsum;
    __syncthreads();
    for (int off = 1; off < 256; off <<= 1) {
        int x = (t >= off) ? sdata[t - off] : 0;
        __syncthreads();
        sdata[t] += x;
        __syncthreads();
    }
    int run = sdata[t] - tsum;
    base[2 * t] = s0 + run;
    base[2 * t + 1] = s0 + run + v0;
    int nbase = b << BSHIFT;
    if (nbase + 2 * t < N)     row_ptr[nbase + 2 * t]     = s0 + run;
    if (nbase + 2 * t + 1 < N) row_ptr[nbase + 2 * t + 1] = s0 + run + v0;
    if (b == 0 && t == 0) row_ptr[N] = E;
    cnt[2 * t] = 0; cnt[2 * t + 1] = 0;
    __syncthreads();
    for (int i = t; i < c; i += 256) {
        unsigned long long p = binned[(size_t)s0 + i];
        int d = (int)(p >> 32) & (BNODES - 1);
        int pos = base[d] + atomicAdd(&cnt[d], 1);
        src_sorted[pos] = (int)(p & 0xffffffffu);
    }
}

// ---------------- per-layer kernels ----------------

// MFMA GEMM: feat(bf16) = bnelu(h) @ W ; el = feat.al ; er = feat.ar
// stats layout: column c sum at [c*SPAD], sumsq at [(64+c)*SPAD]
__global__ __launch_bounds__(256) void gemm64_mfma_kernel(
    const void* __restrict__ hraw, const float* __restrict__ W,
    const float* __restrict__ al, const float* __restrict__ ar,
    const float* __restrict__ stats, const float* __restrict__ g,
    const float* __restrict__ beta, int do_bn, int in_bf16, float invN,
    __hip_bfloat16* __restrict__ feat, float* __restrict__ el, float* __restrict__ er,
    int n) {
    int t = threadIdx.x;
    int lane = t & 63;
    int li = lane & 15;
    int quad = lane >> 4;
    int wv = t >> 6;

    bf16x8 b_hi[2][4], b_lo[2][4];
#pragma unroll
    for (int ks = 0; ks < 2; ks++)
#pragma unroll
        for (int nt = 0; nt < 4; nt++) {
#pragma unroll
            for (int j = 0; j < 8; j++) {
                float w = W[(ks * 32 + quad * 8 + j) * 64 + nt * 16 + li];
                short hi = f2bf(w);
                b_hi[ks][nt][j] = hi;
                b_lo[ks][nt][j] = f2bf(w - bf2f(hi));
            }
        }
    float alv[4], arv[4];
#pragma unroll
    for (int nt = 0; nt < 4; nt++) { alv[nt] = al[nt * 16 + li]; arv[nt] = ar[nt * 16 + li]; }

    float sc[2][8], sh[2][8];
    if (do_bn) {
#pragma unroll
        for (int ks = 0; ks < 2; ks++)
#pragma unroll
            for (int j = 0; j < 8; j++) {
                int k = ks * 32 + quad * 8 + j;
                float mu = stats[k * SPAD] * invN;
                float var = fmaf(-mu, mu, stats[(64 + k) * SPAD] * invN);
                float inv = rsqrtf(var + 1e-5f) * g[k];
                sc[ks][j] = inv;
                sh[ks][j] = beta[k] - mu * inv;
            }
    }

    int ntiles = (n + 15) >> 4;
    for (int tile = blockIdx.x * 4 + wv; tile < ntiles; tile += gridDim.x * 4) {
        int m0 = tile << 4;
        int rrow = m0 + li;
        int crow = (rrow < n) ? rrow : (n - 1);
        bf16x8 a_hi[2], a_lo[2];
#pragma unroll
        for (int ks = 0; ks < 2; ks++) {
            float x[8];
            if (in_bf16) {
                const u32x4* rp = (const u32x4*)((const __hip_bfloat16*)hraw + (size_t)crow * 64 + ks * 32 + quad * 8);
                u32x4 pv = __builtin_nontemporal_load(rp);
                x[0] = __uint_as_float(pv[0] << 16); x[1] = __uint_as_float(pv[0] & 0xffff0000u);
                x[2] = __uint_as_float(pv[1] << 16); x[3] = __uint_as_float(pv[1] & 0xffff0000u);
                x[4] = __uint_as_float(pv[2] << 16); x[5] = __uint_as_float(pv[2] & 0xffff0000u);
                x[6] = __uint_as_float(pv[3] << 16); x[7] = __uint_as_float(pv[3] & 0xffff0000u);
            } else {
                const float* rowp = (const float*)hraw + (size_t)crow * 64 + ks * 32 + quad * 8;
                f32x4 v0 = __builtin_nontemporal_load((const f32x4*)rowp);
                f32x4 v1 = __builtin_nontemporal_load((const f32x4*)(rowp + 4));
                x[0] = v0[0]; x[1] = v0[1]; x[2] = v0[2]; x[3] = v0[3];
                x[4] = v1[0]; x[5] = v1[1]; x[6] = v1[2]; x[7] = v1[3];
            }
#pragma unroll
            for (int j = 0; j < 8; j++) {
                float v = x[j];
                if (do_bn) {
                    v = fmaf(v, sc[ks][j], sh[ks][j]);
                    if (v < 0.f) v = expm1f(v);   // ELU
                }
                short hi = f2bf(v);
                a_hi[ks][j] = hi;
                a_lo[ks][j] = f2bf(v - bf2f(hi));
            }
        }
        f32x4 acc[4];
#pragma unroll
        for (int nt = 0; nt < 4; nt++) acc[nt] = (f32x4){0.f, 0.f, 0.f, 0.f};
#pragma unroll
        for (int ks = 0; ks < 2; ks++)
#pragma unroll
            for (int nt = 0; nt < 4; nt++) {
                acc[nt] = __builtin_amdgcn_mfma_f32_16x16x32_bf16(a_hi[ks], b_hi[ks][nt], acc[nt], 0, 0, 0);
                acc[nt] = __builtin_amdgcn_mfma_f32_16x16x32_bf16(a_lo[ks], b_hi[ks][nt], acc[nt], 0, 0, 0);
                acc[nt] = __builtin_amdgcn_mfma_f32_16x16x32_bf16(a_hi[ks], b_lo[ks][nt], acc[nt], 0, 0, 0);
            }
#pragma unroll
        for (int nt = 0; nt < 4; nt++)
#pragma unroll
            for (int reg = 0; reg < 4; reg++) {
                int wrow = m0 + quad * 4 + reg;
                if (wrow < n) {
                    union { __hip_bfloat16 b; short s; } u;
                    u.s = f2bf(acc[nt][reg]);
                    feat[(size_t)wrow * 64 + nt * 16 + li] = u.b;
                }
            }
        float pl[4], pr[4];
#pragma unroll
        for (int reg = 0; reg < 4; reg++) {
            float l = 0.f, r = 0.f;
#pragma unroll
            for (int nt = 0; nt < 4; nt++) {
                l = fmaf(acc[nt][reg], alv[nt], l);
                r = fmaf(acc[nt][reg], arv[nt], r);
            }
#pragma unroll
            for (int off = 1; off < 16; off <<= 1) {
                l += __shfl_xor(l, off, 64);
                r += __shfl_xor(r, off, 64);
            }
            pl[reg] = l; pr[reg] = r;
        }
        int row = m0 + quad * 4;
        if (li == 0 && row < n)          { el[row] = pl[0]; er[row] = pr[0]; }
        else if (li == 1 && row + 1 < n) { el[row + 1] = pl[1]; er[row + 1] = pr[1]; }
        else if (li == 2 && row + 2 < n) { el[row + 2] = pl[2]; er[row + 2] = pr[2]; }
        else if (li == 3 && row + 3 < n) { el[row + 3] = pl[3]; er[row + 3] = pr[3]; }
    }
}

// Edge score (leaky-relu) + per-dst softmax + alpha (in place).
__global__ __launch_bounds__(256) void attn_kernel(
    const int* __restrict__ row_ptr, const int* __restrict__ src_sorted,
    const float* __restrict__ el, const float* __restrict__ er,
    float* __restrict__ ebuf, int n) {
    int t = threadIdx.x;
    int li = t & 15;
    int node = blockIdx.x * 16 + (t >> 4);
    if (node >= n) return;
    int start = row_ptr[node], end = row_ptr[node + 1];
    float er_n = er[node];

    float m = -INFINITY, s = 0.f;
    for (int i = start + li; i < end; i += 16) {
        float v = el[src_sorted[i]] + er_n;
        v = (v > 0.f) ? v : 0.2f * v;
        ebuf[i] = v;
        float mn = fmaxf(m, v);
        s = s * __expf(m - mn) + __expf(v - mn);
        m = mn;
    }
#pragma unroll
    for (int off = 8; off; off >>= 1) {
        float mo = __shfl_xor(m, off, 64);
        float so = __shfl_xor(s, off, 64);
        float mn = fmaxf(m, mo);
        float sa = (m == -INFINITY) ? 0.f : s * __expf(m - mn);
        float sb = (mo == -INFINITY) ? 0.f : so * __expf(mo - mn);
        s = sa + sb;
        m = mn;
    }
    float inv_s = (s > 0.f) ? 1.f / s : 0.f;
    for (int i = start + li; i < end; i += 16) {
        ebuf[i] = __expf(ebuf[i] - m) * inv_s;
    }
}

// One wave per node (grid-stride); 8 edge-slots of 8 lanes, uint4 bf16
// gathers. BN column stats in registers -> LDS -> 128 atomics per block,
// each counter PADDED to its own cache line (kills same-line serialization).
template<int OUT_BF16>
__global__ __launch_bounds__(256) void aggregate_kernel(
    const int* __restrict__ row_ptr, const int* __restrict__ src_sorted,
    const float* __restrict__ alpha, const __hip_bfloat16* __restrict__ feat,
    const float* __restrict__ bias, void* __restrict__ out,
    float* __restrict__ stats, int n) {
    __shared__ float colsum[128];
    int t = threadIdx.x, lane = t & 63, wv = t >> 6;
    int q = lane >> 3;        // edge slot 0..7
    int li = lane & 7;        // dim octet 0..7
    const uint4* featv = (const uint4*)feat;
    float b0[8];
#pragma unroll
    for (int j = 0; j < 8; j++) b0[j] = bias[li * 8 + j];
    float st_s[8], st_q[8];
#pragma unroll
    for (int j = 0; j < 8; j++) { st_s[j] = 0.f; st_q[j] = 0.f; }

    for (int node = blockIdx.x * 4 + wv; node < n; node += gridDim.x * 4) {
        int start = row_ptr[node], end = row_ptr[node + 1];
        float a0 = 0.f, a1 = 0.f, a2 = 0.f, a3 = 0.f, a4 = 0.f, a5 = 0.f, a6 = 0.f, a7 = 0.f;
        int i = start;
        for (; i + 8 <= end; i += 8) {
            int idx = i + q;
            float a = __builtin_nontemporal_load(alpha + idx);
            int sn = __builtin_nontemporal_load(src_sorted + idx);
            uint4 p = featv[(size_t)sn * 8 + li];
            a0 = fmaf(a, __uint_as_float(p.x << 16), a0);
            a1 = fmaf(a, __uint_as_float(p.x & 0xffff0000u), a1);
            a2 = fmaf(a, __uint_as_float(p.y << 16), a2);
            a3 = fmaf(a, __uint_as_float(p.y & 0xffff0000u), a3);
            a4 = fmaf(a, __uint_as_float(p.z << 16), a4);
            a5 = fmaf(a, __uint_as_float(p.z & 0xffff0000u), a5);
            a6 = fmaf(a, __uint_as_float(p.w << 16), a6);
            a7 = fmaf(a, __uint_as_float(p.w & 0xffff0000u), a7);
        }
        if (i < end) {
            int idx = i + q;
            bool valid = idx < end;
            int idc = valid ? idx : end - 1;
            float a = valid ? alpha[idc] : 0.f;
            int sn = src_sorted[idc];
            uint4 p = featv[(size_t)sn * 8 + li];
            a0 = fmaf(a, __uint_as_float(p.x << 16), a0);
            a1 = fmaf(a, __uint_as_float(p.x & 0xffff0000u), a1);
            a2 = fmaf(a, __uint_as_float(p.y << 16), a2);
            a3 = fmaf(a, __uint_as_float(p.y & 0xffff0000u), a3);
            a4 = fmaf(a, __uint_as_float(p.z << 16), a4);
            a5 = fmaf(a, __uint_as_float(p.z & 0xffff0000u), a5);
            a6 = fmaf(a, __uint_as_float(p.w << 16), a6);
            a7 = fmaf(a, __uint_as_float(p.w & 0xffff0000u), a7);
        }
#pragma unroll
        for (int off = 8; off <= 32; off <<= 1) {
            a0 += __shfl_xor(a0, off, 64);
            a1 += __shfl_xor(a1, off, 64);
            a2 += __shfl_xor(a2, off, 64);
            a3 += __shfl_xor(a3, off, 64);
            a4 += __shfl_xor(a4, off, 64);
            a5 += __shfl_xor(a5, off, 64);
            a6 += __shfl_xor(a6, off, 64);
            a7 += __shfl_xor(a7, off, 64);
        }
        if (q == 0) {
            float o_[8] = {a0 + b0[0], a1 + b0[1], a2 + b0[2], a3 + b0[3],
                           a4 + b0[4], a5 + b0[5], a6 + b0[6], a7 + b0[7]};
#pragma unroll
            for (int j = 0; j < 8; j++) {
                st_s[j] += o_[j];
                st_q[j] = fmaf(o_[j], o_[j], st_q[j]);
            }
            if (OUT_BF16) {
                u32x4 pk;
                pk[0] = ((unsigned)(unsigned short)f2bf(o_[0])) | ((unsigned)(unsigned short)f2bf(o_[1]) << 16);
                pk[1] = ((unsigned)(unsigned short)f2bf(o_[2])) | ((unsigned)(unsigned short)f2bf(o_[3]) << 16);
                pk[2] = ((unsigned)(unsigned short)f2bf(o_[4])) | ((unsigned)(unsigned short)f2bf(o_[5]) << 16);
                pk[3] = ((unsigned)(unsigned short)f2bf(o_[6])) | ((unsigned)(unsigned short)f2bf(o_[7]) << 16);
                __builtin_nontemporal_store(pk, (u32x4*)((__hip_bfloat16*)out + (size_t)node * 64 + li * 8));
            } else {
                f32x4 v0 = {o_[0], o_[1], o_[2], o_[3]};
                f32x4 v1 = {o_[4], o_[5], o_[6], o_[7]};
                f32x4* op = (f32x4*)((float*)out + (size_t)node * 64 + li * 8);
                __builtin_nontemporal_store(v0, op);
                __builtin_nontemporal_store(v1, op + 1);
            }
        }
    }
    // block-level BN stats: LDS combine then one PADDED atomic per column
    if (t < 128) colsum[t] = 0.f;
    __syncthreads();
    if (q == 0) {
#pragma unroll
        for (int j = 0; j < 8; j++) {
            atomicAdd(&colsum[li * 8 + j], st_s[j]);
            atomicAdd(&colsum[64 + li * 8 + j], st_q[j]);
        }
    }
    __syncthreads();
    if (t < 128) atomicAdd(&stats[t * SPAD], colsum[t]);
}

__global__ void bn_apply_kernel(float* __restrict__ h, const float* __restrict__ stats,
                                const float* __restrict__ g, const float* __restrict__ beta,
                                int n, int do_elu) {
    int i = blockIdx.x * blockDim.x + threadIdx.x;
    int total = n * DIM;
    int stride = gridDim.x * blockDim.x;
    float invN = 1.f / (float)n;
    for (; i < total; i += stride) {
        int c = i & 63;
        float mu = stats[c * SPAD] * invN;
        float var = fmaf(-mu, mu, stats[(DIM + c) * SPAD] * invN);
        float x = (h[i] - mu) * rsqrtf(var + 1e-5f) * g[c] + beta[c];
        if (do_elu && x < 0.f) x = expm1f(x);
        h[i] = x;
    }
}

// ---------------- launch ----------------

extern "C" void kernel_launch(void* const* d_in, const int* in_sizes, int n_in,
                              void* d_out, int out_size, void* d_ws, size_t ws_size,
                              hipStream_t stream) {
    const float* nw = (const float*)d_in[0];
    const int* src = (const int*)d_in[2];
    const int* dst = (const int*)d_in[3];
    const int N = in_sizes[0] / DIM;
    const int E = in_sizes[2];
    const float invN = 1.f / (float)N;
    const int nbuck = (N + BNODES - 1) >> BSHIFT;

    char* ws = (char*)d_ws;
    size_t off = 0;
    auto alloc = [&](size_t bytes) -> void* {
        void* p = ws + off;
        off += (bytes + 255) & ~(size_t)255;
        return p;
    };
    int* row_ptr      = (int*)alloc(((size_t)N + 1) * 4);
    int* bucket_cnt   = (int*)alloc(MAXB * 4);
    int* bucket_off   = (int*)alloc(MAXB * 4);
    int* bucket_fill  = (int*)alloc(MAXB * 4);
    unsigned long long* binned = (unsigned long long*)alloc((size_t)E * 8);
    int* src_sorted   = (int*)alloc((size_t)E * 4);
    float* ebuf       = (float*)alloc((size_t)E * 4);
    float* el         = (float*)alloc((size_t)N * 4);
    float* er         = (float*)alloc((size_t)N * 4);
    __hip_bfloat16* feat = (__hip_bfloat16*)alloc((size_t)N * DIM * 2);
    __hip_bfloat16* hbuf = (__hip_bfloat16*)alloc((size_t)N * DIM * 2);
    float* stats      = (float*)alloc(128 * SPAD * 4);   // padded: 1 counter / 64B line

    // CSR build (once; same graph for all 3 layers)
    hipMemsetAsync(bucket_cnt, 0, MAXB * 4, stream);
    bin_count_kernel<<<256, 256, 0, stream>>>(dst, bucket_cnt, E);
    bucket_scan_kernel<<<1, MAXB, 0, stream>>>(bucket_cnt, bucket_off, bucket_fill);
    bin_scatter_kernel<<<(E + CHUNK - 1) / CHUNK, 256, 0, stream>>>(
        src, dst, bucket_off, bucket_fill, binned, E);
    bucket_csr_kernel<<<nbuck, 256, 0, stream>>>(binned, bucket_off, bucket_cnt,
                                                 row_ptr, src_sorted, N, E);

    for (int l = 0; l < 3; l++) {
        const float* W    = (const float*)d_in[4 + 6 * l];
        const float* al   = (const float*)d_in[5 + 6 * l];
        const float* ar   = (const float*)d_in[6 + 6 * l];
        const float* b    = (const float*)d_in[7 + 6 * l];

        gemm64_mfma_kernel<<<1024, 256, 0, stream>>>(
            (l == 0) ? (const void*)nw : (const void*)hbuf, W, al, ar, stats,
            (l == 0) ? al : (const float*)d_in[8 + 6 * (l - 1)],
            (l == 0) ? al : (const float*)d_in[9 + 6 * (l - 1)],
            (l > 0) ? 1 : 0, (l > 0) ? 1 : 0, invN,
            feat, el, er, N);
        hipMemsetAsync(stats, 0, 128 * SPAD * 4, stream);   // after gemm consumed prev stats
        attn_kernel<<<(N + 15) / 16, 256, 0, stream>>>(row_ptr, src_sorted, el, er, ebuf, N);
        if (l < 2) {
            aggregate_kernel<1><<<2048, 256, 0, stream>>>(
                row_ptr, src_sorted, ebuf, feat, b, (void*)hbuf, stats, N);
        } else {
            aggregate_kernel<0><<<2048, 256, 0, stream>>>(
                row_ptr, src_sorted, ebuf, feat, b, d_out, stats, N);
        }
    }
    // final BatchNorm (no ELU) on d_out
    bn_apply_kernel<<<2048, 256, 0, stream>>>((float*)d_out, stats,
                                              (const float*)d_in[8 + 12],
                                              (const float*)d_in[9 + 12],
                                              N, 0);
}

// Round 9
// 539.270 us; speedup vs baseline: 1.1309x; 1.1309x over previous
//
#include <hip/hip_runtime.h>
#include <hip/hip_bf16.h>
#include <math.h>

#define DIM 64
#define BSHIFT 9
#define BNODES 512   // 1 << BSHIFT
#define MAXB 256     // max coarse buckets (N <= 131072)
#define EPT 8
#define CHUNK 2048   // EPT * 256
#define SPAD 16      // stats padding: 1 counter per 64-B cache line

typedef __attribute__((ext_vector_type(8))) short bf16x8;
typedef __attribute__((ext_vector_type(4))) float f32x4;
typedef __attribute__((ext_vector_type(4))) unsigned int u32x4;

__device__ __forceinline__ short f2bf(float x) {
    union { __hip_bfloat16 b; short s; } u;
    u.b = __float2bfloat16(x);
    return u.s;
}
__device__ __forceinline__ float bf2f(short s) {
    return __uint_as_float(((unsigned)(unsigned short)s) << 16);
}

// ---------------- CSR build: binned 2-pass sort ----------------

__global__ void bin_count_kernel(const int* __restrict__ dst, int* __restrict__ bucket_cnt, int E) {
    __shared__ int h[MAXB];
    int t = threadIdx.x;
    h[t] = 0;
    __syncthreads();
    for (int i = blockIdx.x * blockDim.x + t; i < E; i += gridDim.x * blockDim.x)
        atomicAdd(&h[dst[i] >> BSHIFT], 1);
    __syncthreads();
    if (h[t]) atomicAdd(&bucket_cnt[t], h[t]);
}

__global__ void bucket_scan_kernel(const int* __restrict__ bucket_cnt,
                                   int* __restrict__ bucket_off, int* __restrict__ bucket_fill) {
    __shared__ int s[MAXB];
    int t = threadIdx.x;
    int v = bucket_cnt[t];
    s[t] = v;
    __syncthreads();
    for (int off = 1; off < MAXB; off <<= 1) {
        int x = (t >= off) ? s[t - off] : 0;
        __syncthreads();
        s[t] += x;
        __syncthreads();
    }
    bucket_off[t] = s[t] - v;
    bucket_fill[t] = 0;
}

__global__ __launch_bounds__(256) void bin_scatter_kernel(
    const int* __restrict__ src, const int* __restrict__ dst,
    const int* __restrict__ bucket_off, int* __restrict__ bucket_fill,
    unsigned long long* __restrict__ binned, int E) {
    __shared__ int lcnt[MAXB];
    __shared__ int lbase[MAXB];
    int t = threadIdx.x;
    lcnt[t] = 0;
    __syncthreads();
    int base = blockIdx.x * CHUNK;
    unsigned long long pair[EPT];
    int slot[EPT];
#pragma unroll
    for (int j = 0; j < EPT; j++) {
        int idx = base + j * 256 + t;
        if (idx < E) {
            int s = src[idx], d = dst[idx];
            pair[j] = ((unsigned long long)(unsigned)d << 32) | (unsigned)s;
            slot[j] = atomicAdd(&lcnt[d >> BSHIFT], 1);
        } else {
            slot[j] = -1;
        }
    }
    __syncthreads();
    int c = lcnt[t];
    if (c) lbase[t] = atomicAdd(&bucket_fill[t], c);
    __syncthreads();
#pragma unroll
    for (int j = 0; j < EPT; j++) {
        if (slot[j] >= 0) {
            int b = (int)(pair[j] >> 32) >> BSHIFT;
            binned[(size_t)bucket_off[b] + lbase[b] + slot[j]] = pair[j];
        }
    }
}

// One block per bucket: per-node count -> LDS scan -> row_ptr write -> scatter.
__global__ __launch_bounds__(256) void bucket_csr_kernel(
    const unsigned long long* __restrict__ binned, const int* __restrict__ bucket_off,
    const int* __restrict__ bucket_cnt, int* __restrict__ row_ptr,
    int* __restrict__ src_sorted, int N, int E) {
    __shared__ int cnt[BNODES];
    __shared__ int base[BNODES];
    __shared__ int sdata[256];
    int b = blockIdx.x, t = threadIdx.x;
    cnt[t] = 0; cnt[t + 256] = 0;
    __syncthreads();
    int s0 = bucket_off[b], c = bucket_cnt[b];
    for (int i = t; i < c; i += 256) {
        int d = (int)(binned[(size_t)s0 + i] >> 32);
        atomicAdd(&cnt[d & (BNODES - 1)], 1);
    }
    __syncthreads();
    int v0 = cnt[2 * t], v1 = cnt[2 * t + 1];
    int tsum = v0 + v1;
    sdata[t] = tsum;
    __syncthreads();
    for (int off = 1; off < 256; off <<= 1) {
        int x = (t >= off) ? sdata[t - off] : 0;
        __syncthreads();
        sdata[t] += x;
        __syncthreads();
    }
    int run = sdata[t] - tsum;
    base[2 * t] = s0 + run;
    base[2 * t + 1] = s0 + run + v0;
    int nbase = b << BSHIFT;
    if (nbase + 2 * t < N)     row_ptr[nbase + 2 * t]     = s0 + run;
    if (nbase + 2 * t + 1 < N) row_ptr[nbase + 2 * t + 1] = s0 + run + v0;
    if (b == 0 && t == 0) row_ptr[N] = E;
    cnt[2 * t] = 0; cnt[2 * t + 1] = 0;
    __syncthreads();
    for (int i = t; i < c; i += 256) {
        unsigned long long p = binned[(size_t)s0 + i];
        int d = (int)(p >> 32) & (BNODES - 1);
        int pos = base[d] + atomicAdd(&cnt[d], 1);
        src_sorted[pos] = (int)(p & 0xffffffffu);
    }
}

// ---------------- per-layer kernels ----------------

// MFMA GEMM: feat(bf16) = bnelu(h) @ W ; el = feat.al ; er = feat.ar
// stats layout: column c sum at [c*SPAD], sumsq at [(64+c)*SPAD]
__global__ __launch_bounds__(256) void gemm64_mfma_kernel(
    const void* __restrict__ hraw, const float* __restrict__ W,
    const float* __restrict__ al, const float* __restrict__ ar,
    const float* __restrict__ stats, const float* __restrict__ g,
    const float* __restrict__ beta, int do_bn, int in_bf16, float invN,
    __hip_bfloat16* __restrict__ feat, float* __restrict__ el, float* __restrict__ er,
    int n) {
    int t = threadIdx.x;
    int lane = t & 63;
    int li = lane & 15;
    int quad = lane >> 4;
    int wv = t >> 6;

    bf16x8 b_hi[2][4], b_lo[2][4];
#pragma unroll
    for (int ks = 0; ks < 2; ks++)
#pragma unroll
        for (int nt = 0; nt < 4; nt++) {
#pragma unroll
            for (int j = 0; j < 8; j++) {
                float w = W[(ks * 32 + quad * 8 + j) * 64 + nt * 16 + li];
                short hi = f2bf(w);
                b_hi[ks][nt][j] = hi;
                b_lo[ks][nt][j] = f2bf(w - bf2f(hi));
            }
        }
    float alv[4], arv[4];
#pragma unroll
    for (int nt = 0; nt < 4; nt++) { alv[nt] = al[nt * 16 + li]; arv[nt] = ar[nt * 16 + li]; }

    float sc[2][8], sh[2][8];
    if (do_bn) {
#pragma unroll
        for (int ks = 0; ks < 2; ks++)
#pragma unroll
            for (int j = 0; j < 8; j++) {
                int k = ks * 32 + quad * 8 + j;
                float mu = stats[k * SPAD] * invN;
                float var = fmaf(-mu, mu, stats[(64 + k) * SPAD] * invN);
                float inv = rsqrtf(var + 1e-5f) * g[k];
                sc[ks][j] = inv;
                sh[ks][j] = beta[k] - mu * inv;
            }
    }

    int ntiles = (n + 15) >> 4;
    for (int tile = blockIdx.x * 4 + wv; tile < ntiles; tile += gridDim.x * 4) {
        int m0 = tile << 4;
        int rrow = m0 + li;
        int crow = (rrow < n) ? rrow : (n - 1);
        bf16x8 a_hi[2], a_lo[2];
#pragma unroll
        for (int ks = 0; ks < 2; ks++) {
            float x[8];
            if (in_bf16) {
                const u32x4* rp = (const u32x4*)((const __hip_bfloat16*)hraw + (size_t)crow * 64 + ks * 32 + quad * 8);
                u32x4 pv = __builtin_nontemporal_load(rp);
                x[0] = __uint_as_float(pv[0] << 16); x[1] = __uint_as_float(pv[0] & 0xffff0000u);
                x[2] = __uint_as_float(pv[1] << 16); x[3] = __uint_as_float(pv[1] & 0xffff0000u);
                x[4] = __uint_as_float(pv[2] << 16); x[5] = __uint_as_float(pv[2] & 0xffff0000u);
                x[6] = __uint_as_float(pv[3] << 16); x[7] = __uint_as_float(pv[3] & 0xffff0000u);
            } else {
                const float* rowp = (const float*)hraw + (size_t)crow * 64 + ks * 32 + quad * 8;
                f32x4 v0 = __builtin_nontemporal_load((const f32x4*)rowp);
                f32x4 v1 = __builtin_nontemporal_load((const f32x4*)(rowp + 4));
                x[0] = v0[0]; x[1] = v0[1]; x[2] = v0[2]; x[3] = v0[3];
                x[4] = v1[0]; x[5] = v1[1]; x[6] = v1[2]; x[7] = v1[3];
            }
#pragma unroll
            for (int j = 0; j < 8; j++) {
                float v = x[j];
                if (do_bn) {
                    v = fmaf(v, sc[ks][j], sh[ks][j]);
                    if (v < 0.f) v = expm1f(v);   // ELU
                }
                short hi = f2bf(v);
                a_hi[ks][j] = hi;
                a_lo[ks][j] = f2bf(v - bf2f(hi));
            }
        }
        f32x4 acc[4];
#pragma unroll
        for (int nt = 0; nt < 4; nt++) acc[nt] = (f32x4){0.f, 0.f, 0.f, 0.f};
#pragma unroll
        for (int ks = 0; ks < 2; ks++)
#pragma unroll
            for (int nt = 0; nt < 4; nt++) {
                acc[nt] = __builtin_amdgcn_mfma_f32_16x16x32_bf16(a_hi[ks], b_hi[ks][nt], acc[nt], 0, 0, 0);
                acc[nt] = __builtin_amdgcn_mfma_f32_16x16x32_bf16(a_lo[ks], b_hi[ks][nt], acc[nt], 0, 0, 0);
                acc[nt] = __builtin_amdgcn_mfma_f32_16x16x32_bf16(a_hi[ks], b_lo[ks][nt], acc[nt], 0, 0, 0);
            }
#pragma unroll
        for (int nt = 0; nt < 4; nt++)
#pragma unroll
            for (int reg = 0; reg < 4; reg++) {
                int wrow = m0 + quad * 4 + reg;
                if (wrow < n) {
                    union { __hip_bfloat16 b; short s; } u;
                    u.s = f2bf(acc[nt][reg]);
                    feat[(size_t)wrow * 64 + nt * 16 + li] = u.b;
                }
            }
        float pl[4], pr[4];
#pragma unroll
        for (int reg = 0; reg < 4; reg++) {
            float l = 0.f, r = 0.f;
#pragma unroll
            for (int nt = 0; nt < 4; nt++) {
                l = fmaf(acc[nt][reg], alv[nt], l);
                r = fmaf(acc[nt][reg], arv[nt], r);
            }
#pragma unroll
            for (int off = 1; off < 16; off <<= 1) {
                l += __shfl_xor(l, off, 64);
                r += __shfl_xor(r, off, 64);
            }
            pl[reg] = l; pr[reg] = r;
        }
        int row = m0 + quad * 4;
        if (li == 0 && row < n)          { el[row] = pl[0]; er[row] = pr[0]; }
        else if (li == 1 && row + 1 < n) { el[row + 1] = pl[1]; er[row + 1] = pr[1]; }
        else if (li == 2 && row + 2 < n) { el[row + 2] = pl[2]; er[row + 2] = pr[2]; }
        else if (li == 3 && row + 3 < n) { el[row + 3] = pl[3]; er[row + 3] = pr[3]; }
    }
}

// Edge score (leaky-relu) + per-dst softmax + alpha (in place).
__global__ __launch_bounds__(256) void attn_kernel(
    const int* __restrict__ row_ptr, const int* __restrict__ src_sorted,
    const float* __restrict__ el, const float* __restrict__ er,
    float* __restrict__ ebuf, int n) {
    int t = threadIdx.x;
    int li = t & 15;
    int node = blockIdx.x * 16 + (t >> 4);
    if (node >= n) return;
    int start = row_ptr[node], end = row_ptr[node + 1];
    float er_n = er[node];

    float m = -INFINITY, s = 0.f;
    for (int i = start + li; i < end; i += 16) {
        float v = el[src_sorted[i]] + er_n;
        v = (v > 0.f) ? v : 0.2f * v;
        ebuf[i] = v;
        float mn = fmaxf(m, v);
        s = s * __expf(m - mn) + __expf(v - mn);
        m = mn;
    }
#pragma unroll
    for (int off = 8; off; off >>= 1) {
        float mo = __shfl_xor(m, off, 64);
        float so = __shfl_xor(s, off, 64);
        float mn = fmaxf(m, mo);
        float sa = (m == -INFINITY) ? 0.f : s * __expf(m - mn);
        float sb = (mo == -INFINITY) ? 0.f : so * __expf(mo - mn);
        s = sa + sb;
        m = mn;
    }
    float inv_s = (s > 0.f) ? 1.f / s : 0.f;
    for (int i = start + li; i < end; i += 16) {
        ebuf[i] = __expf(ebuf[i] - m) * inv_s;
    }
}

// ROUND-4 structure: ONE node per wave, one-shot blocks (no grid-stride, no
// nt loads, no stats). 8 edge-slots of 8 lanes; uint4 bf16 gathers.
// [R6/R7 lesson: grid-striding this dependent-chain gather halves throughput]
template<int OUT_BF16>
__global__ __launch_bounds__(256) void aggregate_kernel(
    const int* __restrict__ row_ptr, const int* __restrict__ src_sorted,
    const float* __restrict__ alpha, const __hip_bfloat16* __restrict__ feat,
    const float* __restrict__ bias, void* __restrict__ out, int n) {
    int t = threadIdx.x, lane = t & 63;
    int q = lane >> 3;        // edge slot 0..7
    int li = lane & 7;        // dim octet 0..7
    int node = blockIdx.x * 4 + (t >> 6);
    if (node >= n) return;
    int start = row_ptr[node], end = row_ptr[node + 1];
    const uint4* featv = (const uint4*)feat;

    float a0 = 0.f, a1 = 0.f, a2 = 0.f, a3 = 0.f, a4 = 0.f, a5 = 0.f, a6 = 0.f, a7 = 0.f;
    int i = start;
    for (; i + 8 <= end; i += 8) {
        int idx = i + q;
        float a = alpha[idx];
        int sn = src_sorted[idx];
        uint4 p = featv[(size_t)sn * 8 + li];
        a0 = fmaf(a, __uint_as_float(p.x << 16), a0);
        a1 = fmaf(a, __uint_as_float(p.x & 0xffff0000u), a1);
        a2 = fmaf(a, __uint_as_float(p.y << 16), a2);
        a3 = fmaf(a, __uint_as_float(p.y & 0xffff0000u), a3);
        a4 = fmaf(a, __uint_as_float(p.z << 16), a4);
        a5 = fmaf(a, __uint_as_float(p.z & 0xffff0000u), a5);
        a6 = fmaf(a, __uint_as_float(p.w << 16), a6);
        a7 = fmaf(a, __uint_as_float(p.w & 0xffff0000u), a7);
    }
    if (i < end) {
        int idx = i + q;
        bool valid = idx < end;
        int idc = valid ? idx : end - 1;
        float a = valid ? alpha[idc] : 0.f;
        int sn = src_sorted[idc];
        uint4 p = featv[(size_t)sn * 8 + li];
        a0 = fmaf(a, __uint_as_float(p.x << 16), a0);
        a1 = fmaf(a, __uint_as_float(p.x & 0xffff0000u), a1);
        a2 = fmaf(a, __uint_as_float(p.y << 16), a2);
        a3 = fmaf(a, __uint_as_float(p.y & 0xffff0000u), a3);
        a4 = fmaf(a, __uint_as_float(p.z << 16), a4);
        a5 = fmaf(a, __uint_as_float(p.z & 0xffff0000u), a5);
        a6 = fmaf(a, __uint_as_float(p.w << 16), a6);
        a7 = fmaf(a, __uint_as_float(p.w & 0xffff0000u), a7);
    }
#pragma unroll
    for (int off = 8; off <= 32; off <<= 1) {
        a0 += __shfl_xor(a0, off, 64);
        a1 += __shfl_xor(a1, off, 64);
        a2 += __shfl_xor(a2, off, 64);
        a3 += __shfl_xor(a3, off, 64);
        a4 += __shfl_xor(a4, off, 64);
        a5 += __shfl_xor(a5, off, 64);
        a6 += __shfl_xor(a6, off, 64);
        a7 += __shfl_xor(a7, off, 64);
    }
    if (q == 0) {
        const float4* bv = (const float4*)bias;
        float4 b0 = bv[li * 2], b1 = bv[li * 2 + 1];
        float o0 = a0 + b0.x, o1 = a1 + b0.y, o2 = a2 + b0.z, o3 = a3 + b0.w;
        float o4 = a4 + b1.x, o5 = a5 + b1.y, o6 = a6 + b1.z, o7 = a7 + b1.w;
        if (OUT_BF16) {
            uint4 pk;
            pk.x = ((unsigned)(unsigned short)f2bf(o0)) | ((unsigned)(unsigned short)f2bf(o1) << 16);
            pk.y = ((unsigned)(unsigned short)f2bf(o2)) | ((unsigned)(unsigned short)f2bf(o3) << 16);
            pk.z = ((unsigned)(unsigned short)f2bf(o4)) | ((unsigned)(unsigned short)f2bf(o5) << 16);
            pk.w = ((unsigned)(unsigned short)f2bf(o6)) | ((unsigned)(unsigned short)f2bf(o7) << 16);
            *(uint4*)((__hip_bfloat16*)out + (size_t)node * 64 + li * 8) = pk;
        } else {
            float4 v0 = {o0, o1, o2, o3};
            float4 v1 = {o4, o5, o6, o7};
            float4* op = (float4*)((float*)out + (size_t)node * 64 + li * 8);
            op[0] = v0;
            op[1] = v1;
        }
    }
}

// column sums / sumsq (IN_BF16: read bf16 intermediate), padded atomics
template<int IN_BF16>
__global__ __launch_bounds__(256) void bn_stats_kernel(const void* __restrict__ hraw,
                                                       float* __restrict__ stats, int n) {
    __shared__ float ls[256], lss[256];
    int t = threadIdx.x, lane = t & 63;
    int w = blockIdx.x * 4 + (t >> 6);
    int stride = gridDim.x * 4;
    float s = 0.f, ss = 0.f;
    for (int row = w; row < n; row += stride) {
        float v;
        if (IN_BF16) {
            unsigned short u = *((const unsigned short*)hraw + (size_t)row * DIM + lane);
            v = __uint_as_float(((unsigned)u) << 16);
        } else {
            v = *((const float*)hraw + (size_t)row * DIM + lane);
        }
        s += v;
        ss = fmaf(v, v, ss);
    }
    ls[t] = s; lss[t] = ss;
    __syncthreads();
    if (t < 64) {
        float a = ls[t] + ls[t + 64] + ls[t + 128] + ls[t + 192];
        float b = lss[t] + lss[t + 64] + lss[t + 128] + lss[t + 192];
        atomicAdd(&stats[t * SPAD], a);
        atomicAdd(&stats[(64 + t) * SPAD], b);
    }
}

__global__ void bn_apply_kernel(float* __restrict__ h, const float* __restrict__ stats,
                                const float* __restrict__ g, const float* __restrict__ beta,
                                int n, int do_elu) {
    int i = blockIdx.x * blockDim.x + threadIdx.x;
    int total = n * DIM;
    int stride = gridDim.x * blockDim.x;
    float invN = 1.f / (float)n;
    for (; i < total; i += stride) {
        int c = i & 63;
        float mu = stats[c * SPAD] * invN;
        float var = fmaf(-mu, mu, stats[(DIM + c) * SPAD] * invN);
        float x = (h[i] - mu) * rsqrtf(var + 1e-5f) * g[c] + beta[c];
        if (do_elu && x < 0.f) x = expm1f(x);
        h[i] = x;
    }
}

// ---------------- launch ----------------

extern "C" void kernel_launch(void* const* d_in, const int* in_sizes, int n_in,
                              void* d_out, int out_size, void* d_ws, size_t ws_size,
                              hipStream_t stream) {
    const float* nw = (const float*)d_in[0];
    const int* src = (const int*)d_in[2];
    const int* dst = (const int*)d_in[3];
    const int N = in_sizes[0] / DIM;
    const int E = in_sizes[2];
    const float invN = 1.f / (float)N;
    const int nbuck = (N + BNODES - 1) >> BSHIFT;

    char* ws = (char*)d_ws;
    size_t off = 0;
    auto alloc = [&](size_t bytes) -> void* {
        void* p = ws + off;
        off += (bytes + 255) & ~(size_t)255;
        return p;
    };
    int* row_ptr      = (int*)alloc(((size_t)N + 1) * 4);
    int* bucket_cnt   = (int*)alloc(MAXB * 4);
    int* bucket_off   = (int*)alloc(MAXB * 4);
    int* bucket_fill  = (int*)alloc(MAXB * 4);
    unsigned long long* binned = (unsigned long long*)alloc((size_t)E * 8);
    int* src_sorted   = (int*)alloc((size_t)E * 4);
    float* ebuf       = (float*)alloc((size_t)E * 4);
    float* el         = (float*)alloc((size_t)N * 4);
    float* er         = (float*)alloc((size_t)N * 4);
    __hip_bfloat16* feat = (__hip_bfloat16*)alloc((size_t)N * DIM * 2);
    __hip_bfloat16* hbuf = (__hip_bfloat16*)alloc((size_t)N * DIM * 2);
    float* stats      = (float*)alloc(128 * SPAD * 4);   // padded: 1 counter / 64B line

    // CSR build (once; same graph for all 3 layers)
    hipMemsetAsync(bucket_cnt, 0, MAXB * 4, stream);
    bin_count_kernel<<<256, 256, 0, stream>>>(dst, bucket_cnt, E);
    bucket_scan_kernel<<<1, MAXB, 0, stream>>>(bucket_cnt, bucket_off, bucket_fill);
    bin_scatter_kernel<<<(E + CHUNK - 1) / CHUNK, 256, 0, stream>>>(
        src, dst, bucket_off, bucket_fill, binned, E);
    bucket_csr_kernel<<<nbuck, 256, 0, stream>>>(binned, bucket_off, bucket_cnt,
                                                 row_ptr, src_sorted, N, E);

    for (int l = 0; l < 3; l++) {
        const float* W    = (const float*)d_in[4 + 6 * l];
        const float* al   = (const float*)d_in[5 + 6 * l];
        const float* ar   = (const float*)d_in[6 + 6 * l];
        const float* b    = (const float*)d_in[7 + 6 * l];

        gemm64_mfma_kernel<<<1024, 256, 0, stream>>>(
            (l == 0) ? (const void*)nw : (const void*)hbuf, W, al, ar, stats,
            (l == 0) ? al : (const float*)d_in[8 + 6 * (l - 1)],
            (l == 0) ? al : (const float*)d_in[9 + 6 * (l - 1)],
            (l > 0) ? 1 : 0, (l > 0) ? 1 : 0, invN,
            feat, el, er, N);
        hipMemsetAsync(stats, 0, 128 * SPAD * 4, stream);   // after gemm consumed prev stats
        attn_kernel<<<(N + 15) / 16, 256, 0, stream>>>(row_ptr, src_sorted, el, er, ebuf, N);
        if (l < 2) {
            aggregate_kernel<1><<<(N + 3) / 4, 256, 0, stream>>>(
                row_ptr, src_sorted, ebuf, feat, b, (void*)hbuf, N);
            bn_stats_kernel<1><<<512, 256, 0, stream>>>((const void*)hbuf, stats, N);
        } else {
            aggregate_kernel<0><<<(N + 3) / 4, 256, 0, stream>>>(
                row_ptr, src_sorted, ebuf, feat, b, d_out, N);
            bn_stats_kernel<0><<<512, 256, 0, stream>>>((const void*)d_out, stats, N);
        }
    }
    // final BatchNorm (no ELU) on d_out
    bn_apply_kernel<<<2048, 256, 0, stream>>>((float*)d_out, stats,
                                              (const float*)d_in[8 + 12],
                                              (const float*)d_in[9 + 12],
                                              N, 0);
}